// Round 1
// baseline (612.100 us; speedup 1.0000x reference)
//
#include <hip/hip_runtime.h>

#define L_CHUNK 128
#define BATCH   8
#define NHEADS  16
#define DKDIM   64
#define DMODEL  1024   // NHEADS*DKDIM
#define T0CACHE 4096
#define TTOT    4224
#define ROWSTR  8192   // BATCH*NHEADS*DKDIM

typedef __attribute__((ext_vector_type(8))) __bf16 bf16x8;
typedef __attribute__((ext_vector_type(4))) float f32x4;
typedef __attribute__((ext_vector_type(8))) unsigned short us8;

__device__ __forceinline__ unsigned short f2bf(float f) {
    unsigned int u = __float_as_uint(f);
    u += 0x7fffu + ((u >> 16) & 1u);   // round-to-nearest-even
    return (unsigned short)(u >> 16);
}

// ---------------- fp32 -> bf16 conversion (4 elements/thread) ----------------
__global__ void convert_bf16(const float* __restrict__ src,
                             unsigned short* __restrict__ dst, int n4) {
    int i = blockIdx.x * blockDim.x + threadIdx.x;
    if (i < n4) {
        float4 v = ((const float4*)src)[i];
        ushort4 o;
        o.x = f2bf(v.x); o.y = f2bf(v.y); o.z = f2bf(v.z); o.w = f2bf(v.w);
        ((ushort4*)dst)[i] = o;
    }
}

// ---------------- float4 grid-stride copy ----------------
__global__ void copy_f4(const float4* __restrict__ src, float4* __restrict__ dst, int n) {
    int stride = gridDim.x * blockDim.x;
    for (int i = blockIdx.x * blockDim.x + threadIdx.x; i < n; i += stride)
        dst[i] = src[i];
}

// ---------------- bf16 MFMA GEMM: C = A(MxK) * B(KxN) + bias ----------------
// mode 0: plain write C0[row*N + col]
// mode 1: qkv split: col<1024 -> q ws; col<2048 -> K out rows 4096+; else V out
__global__ __launch_bounds__(256) void gemm_bf16(
        const unsigned short* __restrict__ A,
        const unsigned short* __restrict__ B,
        const float* __restrict__ bias,
        float* __restrict__ C0, float* __restrict__ C1, float* __restrict__ C2,
        int K, int N, int mode) {
    __shared__ unsigned short Al[64][40];   // [m][k], pad to 40 (80B rows, 16B aligned)
    __shared__ unsigned short Bl[64][40];   // transposed: [n][k]

    const int tid  = threadIdx.x;
    const int wave = tid >> 6;
    const int lane = tid & 63;
    const int m0 = blockIdx.y * 64;
    const int n0 = blockIdx.x * 64;

    f32x4 zero = {0.f, 0.f, 0.f, 0.f};
    f32x4 acc[4];
    #pragma unroll
    for (int i = 0; i < 4; ++i) acc[i] = zero;

    const int ar = tid >> 2, ac = (tid & 3) * 8;     // A staging: 64 rows x 32 k
    const int bk = tid >> 3, bn = (tid & 7) * 8;     // B staging: 32 k x 64 n
    const int rot = tid & 7;                          // bank-conflict rotation
    const int mrow = wave * 16 + (lane & 15);
    const int koff = (lane >> 4) * 8;

    for (int k0 = 0; k0 < K; k0 += 32) {
        us8 av = *(const us8*)(A + (size_t)(m0 + ar) * K + (k0 + ac));
        us8 bv = *(const us8*)(B + (size_t)(k0 + bk) * N + (n0 + bn));
        *(us8*)(&Al[ar][ac]) = av;
        #pragma unroll
        for (int i = 0; i < 8; ++i) {
            int ii = (i + rot) & 7;
            Bl[bn + ii][bk] = bv[ii];
        }
        __syncthreads();
        bf16x8 af = __builtin_bit_cast(bf16x8, *(const us8*)(&Al[mrow][koff]));
        #pragma unroll
        for (int nt = 0; nt < 4; ++nt) {
            bf16x8 bf = __builtin_bit_cast(bf16x8,
                            *(const us8*)(&Bl[nt * 16 + (lane & 15)][koff]));
            acc[nt] = __builtin_amdgcn_mfma_f32_16x16x32_bf16(af, bf, acc[nt], 0, 0, 0);
        }
        __syncthreads();
    }

    // epilogue: D mapping col=lane&15, row=(lane>>4)*4+reg  [m89/m91 verified]
    const int colt  = lane & 15;
    const int rbase = (lane >> 4) * 4;
    #pragma unroll
    for (int nt = 0; nt < 4; ++nt) {
        int gcol = n0 + nt * 16 + colt;
        float bval = bias[gcol];
        #pragma unroll
        for (int r = 0; r < 4; ++r) {
            int grow = m0 + wave * 16 + rbase + r;
            float val = acc[nt][r] + bval;
            if (mode == 0) {
                C0[(size_t)grow * N + gcol] = val;
            } else {
                int s = gcol >> 10, w = gcol & 1023;
                int l = grow >> 3, b = grow & 7;
                size_t kvoff = (size_t)(T0CACHE + l) * ROWSTR + (size_t)b * DMODEL + w;
                if (s == 0)      C0[(size_t)grow * DMODEL + w] = val;
                else if (s == 1) C1[kvoff] = val;
                else             C2[kvoff] = val;
            }
        }
    }
}

// ---------------- causal self-attention over the chunk ----------------
// grid: 128 blocks (b*16+h); 128 threads = 1 query row each; online softmax.
__global__ __launch_bounds__(128) void attn_kernel(
        const float* __restrict__ qws,
        const float* __restrict__ Kout,
        const float* __restrict__ Vout,
        unsigned short* __restrict__ ob) {
    __shared__ float Kl[128][64];
    __shared__ float Vl[128][64];
    const int t = threadIdx.x;
    const int bh = blockIdx.x;
    const int b = bh >> 4, h = bh & 15;
    const size_t headoff = (size_t)b * DMODEL + (size_t)h * DKDIM;

    const float4* K4 = (const float4*)(Kout + (size_t)T0CACHE * ROWSTR + headoff);
    const float4* V4 = (const float4*)(Vout + (size_t)T0CACHE * ROWSTR + headoff);
    #pragma unroll
    for (int i = 0; i < 16; ++i) {
        int e = i * 128 + t;            // 2048 float4s per array
        int l = e >> 4, d4 = e & 15;    // 16 float4 per row
        ((float4*)Kl)[e] = K4[(size_t)l * (ROWSTR / 4) + d4];
        ((float4*)Vl)[e] = V4[(size_t)l * (ROWSTR / 4) + d4];
    }

    float qr[64];
    const float4* q4 = (const float4*)(qws + headoff + (size_t)t * ROWSTR);
    #pragma unroll
    for (int i = 0; i < 16; ++i) {
        float4 v = q4[i];
        qr[4 * i + 0] = v.x; qr[4 * i + 1] = v.y;
        qr[4 * i + 2] = v.z; qr[4 * i + 3] = v.w;
    }
    __syncthreads();

    float m = -1e30f, lsum = 0.f;
    float o[64];
    #pragma unroll
    for (int d = 0; d < 64; ++d) o[d] = 0.f;

    for (int j = 0; j < 128; ++j) {
        float s = 0.f;
        #pragma unroll
        for (int d = 0; d < 64; ++d) s = fmaf(qr[d], Kl[j][d], s);
        s *= 0.125f;                    // 1/sqrt(DK)
        const bool valid = (j <= t);    // causal within chunk (window == chunk)
        float mn = valid ? fmaxf(m, s) : m;
        float scale = __expf(m - mn);   // exp(0)=1 when unchanged; exp(-1e30)=0 first iter
        float p = valid ? __expf(s - mn) : 0.f;
        lsum = lsum * scale + p;
        #pragma unroll
        for (int d = 0; d < 64; ++d) o[d] = fmaf(o[d], scale, p * Vl[j][d]);
        m = mn;
    }
    float inv = 1.f / lsum;
    unsigned short* op = ob + headoff + (size_t)t * ROWSTR;
    #pragma unroll
    for (int d = 0; d < 64; ++d) op[d] = f2bf(o[d] * inv);
}

extern "C" void kernel_launch(void* const* d_in, const int* in_sizes, int n_in,
                              void* d_out, int out_size, void* d_ws, size_t ws_size,
                              hipStream_t stream) {
    const float* x     = (const float*)d_in[0];
    const float* Kc    = (const float*)d_in[1];
    const float* Vc    = (const float*)d_in[2];
    const float* qkv_w = (const float*)d_in[3];
    const float* qkv_b = (const float*)d_in[4];
    const float* out_w = (const float*)d_in[5];
    const float* out_b = (const float*)d_in[6];

    float* y    = (float*)d_out;                                   // (L,B,D) = 1,048,576
    float* Kout = y + (size_t)L_CHUNK * BATCH * DMODEL;            // (T,B,NH,DK) = 34,603,008
    float* Vout = Kout + (size_t)TTOT * ROWSTR;

    char* ws = (char*)d_ws;
    unsigned short* xb  = (unsigned short*)ws;                     // 2 MB
    unsigned short* wb  = (unsigned short*)(ws + (size_t)(2  << 20)); // 6 MB
    unsigned short* owb = (unsigned short*)(ws + (size_t)(8  << 20)); // 2 MB
    float*          qws = (float*)(ws + (size_t)(10 << 20));       // 4 MB
    unsigned short* ob  = (unsigned short*)(ws + (size_t)(14 << 20)); // 2 MB

    // bf16 conversions
    convert_bf16<<<1024, 256, 0, stream>>>(x,     xb,  262144);
    convert_bf16<<<3072, 256, 0, stream>>>(qkv_w, wb,  786432);
    convert_bf16<<<1024, 256, 0, stream>>>(out_w, owb, 262144);

    // cache copies into output K/V rows [0, 4096)
    copy_f4<<<4096, 256, 0, stream>>>((const float4*)Kc, (float4*)Kout, 8388608);
    copy_f4<<<4096, 256, 0, stream>>>((const float4*)Vc, (float4*)Vout, 8388608);

    // qkv GEMM: (1024x1024)@(1024x3072); q->ws, k/v -> output rows [4096, 4224)
    gemm_bf16<<<dim3(48, 16), 256, 0, stream>>>(xb, wb, qkv_b, qws, Kout, Vout,
                                                DMODEL, 3 * DMODEL, 1);

    // attention over the chunk
    attn_kernel<<<128, 128, 0, stream>>>(qws, Kout, Vout, ob);

    // out GEMM: (1024x1024)@(1024x1024) + out_b -> y
    gemm_bf16<<<dim3(16, 16), 256, 0, stream>>>(ob, owb, out_b, y, nullptr, nullptr,
                                                DMODEL, DMODEL, 0);
}

// Round 2
// 524.709 us; speedup vs baseline: 1.1666x; 1.1666x over previous
//
#include <hip/hip_runtime.h>

#define L_CHUNK 128
#define BATCH   8
#define NHEADS  16
#define DKDIM   64
#define DMODEL  1024   // NHEADS*DKDIM
#define T0CACHE 4096
#define TTOT    4224
#define ROWSTR  8192   // BATCH*NHEADS*DKDIM

typedef __attribute__((ext_vector_type(8))) __bf16 bf16x8;
typedef __attribute__((ext_vector_type(4))) float f32x4;
typedef __attribute__((ext_vector_type(8))) unsigned short us8;

__device__ __forceinline__ unsigned short f2bf(float f) {
    unsigned int u = __float_as_uint(f);
    u += 0x7fffu + ((u >> 16) & 1u);   // round-to-nearest-even
    return (unsigned short)(u >> 16);
}

// ---------------- fused fp32 -> bf16 conversion of x, qkv_w, out_w ----------------
__global__ __launch_bounds__(256) void prep_convert(
        const float* __restrict__ x, const float* __restrict__ qkv_w,
        const float* __restrict__ out_w,
        unsigned short* __restrict__ xb, unsigned short* __restrict__ wb,
        unsigned short* __restrict__ owb) {
    int idx = blockIdx.x * 256 + threadIdx.x;   // over 1,310,720 float4
    const float4* s4; ushort4* d4; int rel;
    if (idx < 262144)        { s4 = (const float4*)x;     d4 = (ushort4*)xb;  rel = idx; }
    else if (idx < 1048576)  { s4 = (const float4*)qkv_w; d4 = (ushort4*)wb;  rel = idx - 262144; }
    else                     { s4 = (const float4*)out_w; d4 = (ushort4*)owb; rel = idx - 1048576; }
    float4 v = s4[rel];
    ushort4 o; o.x = f2bf(v.x); o.y = f2bf(v.y); o.z = f2bf(v.z); o.w = f2bf(v.w);
    d4[rel] = o;
}

// ---------------- GEMM body: C = A(MxK bf16) * B(KxN bf16) + bias ----------------
// MODE 0: fp32 C -> Cf[row*N+col].  MODE 1: qkv split: q->bf16 Cq, K/V->fp32 C1/C2.
template<int MODE>
__device__ __forceinline__ void gemm_body(
        int bx, int by,
        const unsigned short* __restrict__ A,
        const unsigned short* __restrict__ B,
        const float* __restrict__ bias,
        float* __restrict__ Cf, unsigned short* __restrict__ Cq,
        float* __restrict__ C1, float* __restrict__ C2,
        int K, int N) {
    __shared__ unsigned short Al[64][40];
    __shared__ unsigned short Bl[64][40];

    const int tid  = threadIdx.x;
    const int wave = tid >> 6;
    const int lane = tid & 63;
    const int m0 = by * 64;
    const int n0 = bx * 64;

    f32x4 zero = {0.f, 0.f, 0.f, 0.f};
    f32x4 acc[4];
    #pragma unroll
    for (int i = 0; i < 4; ++i) acc[i] = zero;

    const int ar = tid >> 2, ac = (tid & 3) * 8;
    const int bk = tid >> 3, bn = (tid & 7) * 8;
    const int rot = tid & 7;
    const int mrow = wave * 16 + (lane & 15);
    const int koff = (lane >> 4) * 8;

    for (int k0 = 0; k0 < K; k0 += 32) {
        us8 av = *(const us8*)(A + (size_t)(m0 + ar) * K + (k0 + ac));
        us8 bv = *(const us8*)(B + (size_t)(k0 + bk) * N + (n0 + bn));
        *(us8*)(&Al[ar][ac]) = av;
        #pragma unroll
        for (int i = 0; i < 8; ++i) {
            int ii = (i + rot) & 7;
            Bl[bn + ii][bk] = bv[ii];
        }
        __syncthreads();
        bf16x8 af = __builtin_bit_cast(bf16x8, *(const us8*)(&Al[mrow][koff]));
        #pragma unroll
        for (int nt = 0; nt < 4; ++nt) {
            bf16x8 bf = __builtin_bit_cast(bf16x8,
                            *(const us8*)(&Bl[nt * 16 + (lane & 15)][koff]));
            acc[nt] = __builtin_amdgcn_mfma_f32_16x16x32_bf16(af, bf, acc[nt], 0, 0, 0);
        }
        __syncthreads();
    }

    const int colt  = lane & 15;
    const int rbase = (lane >> 4) * 4;
    #pragma unroll
    for (int nt = 0; nt < 4; ++nt) {
        int gcol = n0 + nt * 16 + colt;
        float bval = bias[gcol];
        #pragma unroll
        for (int r = 0; r < 4; ++r) {
            int grow = m0 + wave * 16 + rbase + r;
            float val = acc[nt][r] + bval;
            if (MODE == 0) {
                Cf[(size_t)grow * N + gcol] = val;
            } else {
                int s = gcol >> 10, w = gcol & 1023;
                int l = grow >> 3, b = grow & 7;
                size_t kvoff = (size_t)(T0CACHE + l) * ROWSTR + (size_t)b * DMODEL + w;
                if (s == 0)      Cq[(size_t)grow * DMODEL + w] = f2bf(val);
                else if (s == 1) C1[kvoff] = val;
                else             C2[kvoff] = val;
            }
        }
    }
}

// ---------------- fused: qkv GEMM (768 blocks) + cache copies (2560 blocks) ----------------
// Interleave: in [0,3072): (g&3)==0 -> gemm #(g>>2); else copy #(g - (g>>2) - 1).
// In [3072,3328): copy #(g - 768).
__global__ __launch_bounds__(256) void qkv_and_copy(
        const unsigned short* __restrict__ xb,
        const unsigned short* __restrict__ wb,
        const float* __restrict__ qkv_b,
        unsigned short* __restrict__ qb,
        float* __restrict__ Kout, float* __restrict__ Vout,
        const float4* __restrict__ Kc, const float4* __restrict__ Vc) {
    const int g = blockIdx.x;
    const bool isGemm = (g < 3072) && ((g & 3) == 0);
    if (isGemm) {
        int gi = g >> 2;                 // 0..767
        gemm_body<1>(gi % 48, gi / 48, xb, wb, qkv_b, nullptr, qb, Kout, Vout,
                     DMODEL, 3 * DMODEL);
    } else {
        int cid = (g < 3072) ? (g - (g >> 2) - 1) : (g - 768);   // 0..2559
        const int stride = 2560 * 256;
        float4* Kd = (float4*)Kout;
        float4* Vd = (float4*)Vout;
        for (int e = cid * 256 + threadIdx.x; e < 8388608; e += stride) Kd[e] = Kc[e];
        for (int e = cid * 256 + threadIdx.x; e < 8388608; e += stride) Vd[e] = Vc[e];
    }
}

// ---------------- out GEMM ----------------
__global__ __launch_bounds__(256) void out_gemm(
        const unsigned short* __restrict__ ob,
        const unsigned short* __restrict__ owb,
        const float* __restrict__ out_b, float* __restrict__ y) {
    gemm_body<0>(blockIdx.x, blockIdx.y, ob, owb, out_b, y, nullptr, nullptr, nullptr,
                 DMODEL, DMODEL);
}

// ---------------- MFMA flash attention over the chunk ----------------
// 256 blocks = (b,h,qhalf); 256 threads = 4 waves; wave w owns 16 query rows.
__global__ __launch_bounds__(256) void attn_mfma(
        const unsigned short* __restrict__ qb,   // bf16 [(l*8+b)*1024 + h*64 + d]
        const float* __restrict__ Kout,
        const float* __restrict__ Vout,
        unsigned short* __restrict__ ob) {
    __shared__ unsigned short Kb[128][72];       // [key][d], pad 72
    __shared__ unsigned short Vt[64][136];       // [d][key], pad 136
    __shared__ unsigned short Pb[4][16][136];    // per wave [row][key]

    const int tid  = threadIdx.x;
    const int wave = tid >> 6, lane = tid & 63;
    const int qh = blockIdx.x & 1, bh = blockIdx.x >> 1;
    const int b = bh >> 4, h = bh & 15;
    const int q0 = qh * 64;
    const size_t base = (size_t)T0CACHE * ROWSTR + (size_t)b * DMODEL + h * DKDIM;

    // stage K row-major + V transposed, fp32 -> bf16 (always full 128 keys)
    for (int e = tid; e < 2048; e += 256) {      // 128 rows x 16 float4
        int j = e >> 4, d4 = (e & 15) * 4;
        float4 kv = *(const float4*)(Kout + base + (size_t)j * ROWSTR + d4);
        ushort4 u; u.x = f2bf(kv.x); u.y = f2bf(kv.y); u.z = f2bf(kv.z); u.w = f2bf(kv.w);
        *(ushort4*)&Kb[j][d4] = u;
        float4 vv = *(const float4*)(Vout + base + (size_t)j * ROWSTR + d4);
        Vt[d4 + 0][j] = f2bf(vv.x); Vt[d4 + 1][j] = f2bf(vv.y);
        Vt[d4 + 2][j] = f2bf(vv.z); Vt[d4 + 3][j] = f2bf(vv.w);
    }

    // Q fragments (A-layout: m=lane&15, k=(lane>>4)*8+j), 2 k-steps of 32
    const int qrow = q0 + wave * 16 + (lane & 15);
    const size_t arow = (size_t)(qrow * 8 + b) * DMODEL + h * DKDIM;
    bf16x8 qa0 = __builtin_bit_cast(bf16x8, *(const us8*)(qb + arow + (lane >> 4) * 8));
    bf16x8 qa1 = __builtin_bit_cast(bf16x8, *(const us8*)(qb + arow + 32 + (lane >> 4) * 8));
    __syncthreads();

    // S = Q K^T : 8 key-tiles of 16
    f32x4 sacc[8];
    f32x4 zero = {0.f, 0.f, 0.f, 0.f};
    #pragma unroll
    for (int t = 0; t < 8; ++t) sacc[t] = zero;
    #pragma unroll
    for (int t = 0; t < 8; ++t) {
        bf16x8 k0 = __builtin_bit_cast(bf16x8,
                        *(const us8*)(&Kb[t * 16 + (lane & 15)][(lane >> 4) * 8]));
        bf16x8 k1 = __builtin_bit_cast(bf16x8,
                        *(const us8*)(&Kb[t * 16 + (lane & 15)][32 + (lane >> 4) * 8]));
        sacc[t] = __builtin_amdgcn_mfma_f32_16x16x32_bf16(qa0, k0, sacc[t], 0, 0, 0);
        sacc[t] = __builtin_amdgcn_mfma_f32_16x16x32_bf16(qa1, k1, sacc[t], 0, 0, 0);
    }

    // mask + row softmax. C-layout: col=lane&15, row=(lane>>4)*4+reg.
    const int col = lane & 15;
    float mrow[4], lsum[4], inv[4];
    #pragma unroll
    for (int r = 0; r < 4; ++r) mrow[r] = -3e38f;
    #pragma unroll
    for (int t = 0; t < 8; ++t) {
        #pragma unroll
        for (int r = 0; r < 4; ++r) {
            int key = t * 16 + col;
            int qi  = q0 + wave * 16 + (lane >> 4) * 4 + r;
            float v = sacc[t][r] * 0.125f;
            if (key > qi) v = -1e9f;
            sacc[t][r] = v;
            mrow[r] = fmaxf(mrow[r], v);
        }
    }
    #pragma unroll
    for (int r = 0; r < 4; ++r) {
        #pragma unroll
        for (int off = 1; off < 16; off <<= 1)
            mrow[r] = fmaxf(mrow[r], __shfl_xor(mrow[r], off, 64));
        lsum[r] = 0.f;
    }
    #pragma unroll
    for (int t = 0; t < 8; ++t) {
        #pragma unroll
        for (int r = 0; r < 4; ++r) {
            float p = __expf(sacc[t][r] - mrow[r]);
            lsum[r] += p;
            Pb[wave][(lane >> 4) * 4 + r][t * 16 + col] = f2bf(p);
        }
    }
    #pragma unroll
    for (int r = 0; r < 4; ++r) {
        #pragma unroll
        for (int off = 1; off < 16; off <<= 1)
            lsum[r] += __shfl_xor(lsum[r], off, 64);
        inv[r] = 1.f / lsum[r];
    }
    __syncthreads();

    // O = P V : P in A-layout from LDS, V^T gives B-layout b128 reads
    bf16x8 pa[4];
    #pragma unroll
    for (int ks = 0; ks < 4; ++ks)
        pa[ks] = __builtin_bit_cast(bf16x8,
                     *(const us8*)(&Pb[wave][lane & 15][ks * 32 + (lane >> 4) * 8]));
    f32x4 oacc[4];
    #pragma unroll
    for (int n = 0; n < 4; ++n) oacc[n] = zero;
    #pragma unroll
    for (int n = 0; n < 4; ++n) {
        #pragma unroll
        for (int ks = 0; ks < 4; ++ks) {
            bf16x8 vb = __builtin_bit_cast(bf16x8,
                            *(const us8*)(&Vt[n * 16 + (lane & 15)][ks * 32 + (lane >> 4) * 8]));
            oacc[n] = __builtin_amdgcn_mfma_f32_16x16x32_bf16(pa[ks], vb, oacc[n], 0, 0, 0);
        }
    }

    // store O (bf16) to ob rows (l*8+b), cols h*64 + d
    #pragma unroll
    for (int n = 0; n < 4; ++n) {
        #pragma unroll
        for (int r = 0; r < 4; ++r) {
            int qi = q0 + wave * 16 + (lane >> 4) * 4 + r;
            int d  = n * 16 + col;
            ob[(size_t)(qi * 8 + b) * DMODEL + h * DKDIM + d] = f2bf(oacc[n][r] * inv[r]);
        }
    }
}

extern "C" void kernel_launch(void* const* d_in, const int* in_sizes, int n_in,
                              void* d_out, int out_size, void* d_ws, size_t ws_size,
                              hipStream_t stream) {
    const float* x     = (const float*)d_in[0];
    const float* Kc    = (const float*)d_in[1];
    const float* Vc    = (const float*)d_in[2];
    const float* qkv_w = (const float*)d_in[3];
    const float* qkv_b = (const float*)d_in[4];
    const float* out_w = (const float*)d_in[5];
    const float* out_b = (const float*)d_in[6];

    float* y    = (float*)d_out;
    float* Kout = y + (size_t)L_CHUNK * BATCH * DMODEL;
    float* Vout = Kout + (size_t)TTOT * ROWSTR;

    char* ws = (char*)d_ws;
    unsigned short* xb  = (unsigned short*)ws;                        // 2 MB
    unsigned short* wb  = (unsigned short*)(ws + (size_t)(2  << 20)); // 6 MB
    unsigned short* owb = (unsigned short*)(ws + (size_t)(8  << 20)); // 2 MB
    unsigned short* qb  = (unsigned short*)(ws + (size_t)(10 << 20)); // 2 MB (bf16 q)
    unsigned short* ob  = (unsigned short*)(ws + (size_t)(12 << 20)); // 2 MB

    prep_convert<<<5120, 256, 0, stream>>>(x, qkv_w, out_w, xb, wb, owb);

    qkv_and_copy<<<3328, 256, 0, stream>>>(xb, wb, qkv_b, qb, Kout, Vout,
                                           (const float4*)Kc, (const float4*)Vc);

    attn_mfma<<<256, 256, 0, stream>>>(qb, Kout, Vout, ob);

    out_gemm<<<dim3(16, 16), 256, 0, stream>>>(ob, owb, out_b, y);
}